// Round 7
// baseline (55.191 us; speedup 1.0000x reference)
//
#include <hip/hip_runtime.h>

// out[i, p, a, b] = sum_{m,n} A[i, m, a] * B[i, n, b] * C[m, n, p]
// A: (600000, 3, 3), B: (600000, 5, 5), C: (3, 5, 5), out: (600000, 5, 15)
//
// Block = 320 threads = 64 atoms x 5 p-values, tile = 64 atoms.
// Single-buffered sAB (27.9 KB LDS -> 5 blocks/CU, 25 waves).
// Wave-local flush: wave w's sO slice [960w, 960w+960) is written only by
// its own lanes and is contiguous in global -> flush needs only
// lgkmcnt(0), NO block barrier. The 2 remaining lgkm-only barriers protect
// shared sAB around the stage-write; the flush (LDS reads + nt stores)
// runs outside the barrier convoy.
//   top    : issue next tile's global loads into regs (nontemporal)
//   compute: 120 FMA -> 15 outs to sO[tid*15..]
//   lgkm(0): own-wave sO writes visible to own lanes
//   flush  : wave-local, 4x b128 read + nt f32x4 store, coalesced
//   BAR(lgkm)  <- all waves past compute (sAB reads done)
//   stage  : ds_write staged regs -> sAB
//   BAR(lgkm)  <- stage visible; global stores never drained in-loop

#define N_ATOMS 600000
#define NTILES (N_ATOMS / 64)   // 9375 exact
#define A_FL 576                // 64*9
#define AB_FL 2176              // 576 + 1600
#define O_FL 4800               // 64*75
#define GRID 2048

typedef float f32x4 __attribute__((ext_vector_type(4)));

__device__ __forceinline__ void bar_lgkm() {
    asm volatile("s_waitcnt lgkmcnt(0)" ::: "memory");
    __builtin_amdgcn_s_barrier();
    asm volatile("" ::: "memory");
}

__global__ __launch_bounds__(320) void tb_kernel(const float* __restrict__ A,
                                                 const float* __restrict__ B,
                                                 const float* __restrict__ C,
                                                 float* __restrict__ out) {
    __shared__ __align__(16) float sAB[AB_FL];
    __shared__ __align__(16) float sO[O_FL];

    const int tid   = threadIdx.x;
    const int i_loc = tid / 5;         // 0..63
    const int p     = tid - i_loc * 5; // 0..4
    const int wv    = tid >> 6;        // wave id 0..4
    const int lane  = tid & 63;

    // C[:, :, p] in 15 registers (uniform across tiles)
    float cr[3][5];
    #pragma unroll
    for (int m = 0; m < 3; ++m)
        #pragma unroll
        for (int n = 0; n < 5; ++n)
            cr[m][n] = C[m * 25 + n * 5 + p];

    // ---- prologue: stage tile0 ----
    int tile = blockIdx.x;
    {
        const int i0 = tile * 64;
        #pragma unroll
        for (int jj = 0; jj < 2; ++jj) {
            int j = tid + jj * 320;
            if (j < 544) {
                int f0 = j * 4;
                f32x4 v = (f0 < A_FL)
                    ? __builtin_nontemporal_load(reinterpret_cast<const f32x4*>(A + (size_t)i0 * 9 + f0))
                    : __builtin_nontemporal_load(reinterpret_cast<const f32x4*>(B + (size_t)i0 * 25 + (f0 - A_FL)));
                *reinterpret_cast<f32x4*>(&sAB[f0]) = v;
            }
        }
    }
    bar_lgkm();

    const bool g1v = (tid + 320) < 544;  // second stage slot valid for tid<224
    for (; tile < NTILES; tile += GRID) {
        const int  next      = tile + GRID;
        const bool have_next = next < NTILES;

        // ---- issue next tile's loads into registers (nontemporal) ----
        f32x4 g0, g1;
        if (have_next) {
            const int i0 = next * 64;
            const int f0 = tid * 4;                  // 0..1276
            g0 = (f0 < A_FL)
                ? __builtin_nontemporal_load(reinterpret_cast<const f32x4*>(A + (size_t)i0 * 9 + f0))
                : __builtin_nontemporal_load(reinterpret_cast<const f32x4*>(B + (size_t)i0 * 25 + (f0 - A_FL)));
            if (g1v) {
                const int f1 = (tid + 320) * 4;      // 1280..2172, always B side
                g1 = __builtin_nontemporal_load(reinterpret_cast<const f32x4*>(B + (size_t)i0 * 25 + (f1 - A_FL)));
            }
        }

        // ---- compute from sAB ----
        float av[9];
        #pragma unroll
        for (int k = 0; k < 9; ++k) av[k] = sAB[i_loc * 9 + k];
        float bv[25];
        #pragma unroll
        for (int k = 0; k < 25; ++k) bv[k] = sAB[A_FL + i_loc * 25 + k];

        // T[m][b] = sum_n bv[n][b] * cr[m][n]
        float T[3][5];
        #pragma unroll
        for (int m = 0; m < 3; ++m) {
            #pragma unroll
            for (int b = 0; b < 5; ++b) {
                float t = 0.0f;
                #pragma unroll
                for (int n = 0; n < 5; ++n)
                    t = fmaf(bv[n * 5 + b], cr[m][n], t);
                T[m][b] = t;
            }
        }
        // out[a][b] = sum_m av[m][a] * T[m][b]
        #pragma unroll
        for (int a = 0; a < 3; ++a) {
            #pragma unroll
            for (int b = 0; b < 5; ++b) {
                float acc = 0.0f;
                #pragma unroll
                for (int m = 0; m < 3; ++m)
                    acc = fmaf(av[m * 3 + a], T[m][b], acc);
                sO[tid * 15 + a * 5 + b] = acc;
            }
        }

        // own-wave sO writes complete (wave-local ordering, no barrier)
        asm volatile("s_waitcnt lgkmcnt(0)" ::: "memory");

        // ---- wave-local flush: slice [240*wv, 240*wv+240) of f32x4 chunks ----
        {
            const f32x4* sOv = reinterpret_cast<const f32x4*>(sO);
            f32x4* obase = reinterpret_cast<f32x4*>(out + (size_t)tile * O_FL);
            #pragma unroll
            for (int k = 0; k < 4; ++k) {
                int c = lane + 64 * k;          // 0..255
                if (c < 240) {
                    int chunk = 240 * wv + c;   // within this wave's slice
                    f32x4 v = sOv[chunk];
                    __builtin_nontemporal_store(v, obase + chunk);
                }
            }
        }

        bar_lgkm();   // B1: all waves past compute (sAB reads done)

        // ---- stage-write regs -> sAB (same buffer; reads all done) ----
        if (have_next) {
            *reinterpret_cast<f32x4*>(&sAB[tid * 4]) = g0;
            if (g1v)
                *reinterpret_cast<f32x4*>(&sAB[(tid + 320) * 4]) = g1;
        }

        bar_lgkm();   // B2: stage visible; stores keep flying
    }
}

extern "C" void kernel_launch(void* const* d_in, const int* in_sizes, int n_in,
                              void* d_out, int out_size, void* d_ws, size_t ws_size,
                              hipStream_t stream) {
    const float* A = (const float*)d_in[0];
    const float* B = (const float*)d_in[1];
    const float* C = (const float*)d_in[2];
    float* out = (float*)d_out;

    tb_kernel<<<GRID, 320, 0, stream>>>(A, B, C, out);
}

// Round 8
// 44.736 us; speedup vs baseline: 1.2337x; 1.2337x over previous
//
#include <hip/hip_runtime.h>

// out[i, p, a, b] = sum_{m,n} A[i, m, a] * B[i, n, b] * C[m, n, p]
// A: (600000, 3, 3), B: (600000, 5, 5), C: (3, 5, 5), out: (600000, 5, 15)
//
// Round-6 structure (known-good 44.7 us, 5.68 TB/s):
// Block = 320 threads = 64 atoms x 5 p-values, tile = 64 atoms.
// SINGLE-buffered sAB (reg-hop makes dbuf redundant) -> 27.9 KB LDS
// -> 5 blocks/CU (25 waves/CU).
//   top    : issue next tile's global loads into regs (PLAIN loads --
//            r7 showed nt-loads + pre-barrier flush cost 23%)
//   compute: read A/B rows from sAB, 120 FMA, 15 outs -> sO
//   BAR(lgkm)                        <- no store drain
//   flush  : sO -> global, nontemporal f32x4, all 5 waves concurrently
//   stage  : ds_write staged regs -> sAB (wait = counted vmcnt(4), not
//            a store drain; prior-tile stores get a full tile of slack)
//   BAR(lgkm)

#define N_ATOMS 600000
#define NTILES (N_ATOMS / 64)   // 9375 exact
#define A_FL 576                // 64*9
#define AB_FL 2176              // 576 + 1600
#define O_FL 4800               // 64*75
#define GRID 2048

typedef float f32x4 __attribute__((ext_vector_type(4)));

__device__ __forceinline__ void bar_lgkm() {
    asm volatile("s_waitcnt lgkmcnt(0)" ::: "memory");
    __builtin_amdgcn_s_barrier();
    asm volatile("" ::: "memory");
}

__global__ __launch_bounds__(320) void tb_kernel(const float* __restrict__ A,
                                                 const float* __restrict__ B,
                                                 const float* __restrict__ C,
                                                 float* __restrict__ out) {
    __shared__ __align__(16) float sAB[AB_FL];
    __shared__ __align__(16) float sO[O_FL];

    const int tid   = threadIdx.x;
    const int i_loc = tid / 5;         // 0..63
    const int p     = tid - i_loc * 5; // 0..4

    // C[:, :, p] in 15 registers (uniform across tiles)
    float cr[3][5];
    #pragma unroll
    for (int m = 0; m < 3; ++m)
        #pragma unroll
        for (int n = 0; n < 5; ++n)
            cr[m][n] = C[m * 25 + n * 5 + p];

    // ---- prologue: stage tile0 ----
    int tile = blockIdx.x;
    {
        const int i0 = tile * 64;
        #pragma unroll
        for (int jj = 0; jj < 2; ++jj) {
            int j = tid + jj * 320;
            if (j < 544) {
                int f0 = j * 4;
                f32x4 v = (f0 < A_FL)
                    ? *reinterpret_cast<const f32x4*>(A + (size_t)i0 * 9 + f0)
                    : *reinterpret_cast<const f32x4*>(B + (size_t)i0 * 25 + (f0 - A_FL));
                *reinterpret_cast<f32x4*>(&sAB[f0]) = v;
            }
        }
    }
    bar_lgkm();

    const bool g1v = (tid + 320) < 544;  // second stage slot valid for tid<224
    for (; tile < NTILES; tile += GRID) {
        const int  next      = tile + GRID;
        const bool have_next = next < NTILES;

        // ---- issue next tile's loads into registers ----
        f32x4 g0, g1;
        if (have_next) {
            const int i0 = next * 64;
            const int f0 = tid * 4;                  // 0..1276
            g0 = (f0 < A_FL)
                ? *reinterpret_cast<const f32x4*>(A + (size_t)i0 * 9 + f0)
                : *reinterpret_cast<const f32x4*>(B + (size_t)i0 * 25 + (f0 - A_FL));
            if (g1v) {
                const int f1 = (tid + 320) * 4;      // 1280..2172, always B side
                g1 = *reinterpret_cast<const f32x4*>(B + (size_t)i0 * 25 + (f1 - A_FL));
            }
        }

        // ---- compute from sAB ----
        float av[9];
        #pragma unroll
        for (int k = 0; k < 9; ++k) av[k] = sAB[i_loc * 9 + k];
        float bv[25];
        #pragma unroll
        for (int k = 0; k < 25; ++k) bv[k] = sAB[A_FL + i_loc * 25 + k];

        // T[m][b] = sum_n bv[n][b] * cr[m][n]
        float T[3][5];
        #pragma unroll
        for (int m = 0; m < 3; ++m) {
            #pragma unroll
            for (int b = 0; b < 5; ++b) {
                float t = 0.0f;
                #pragma unroll
                for (int n = 0; n < 5; ++n)
                    t = fmaf(bv[n * 5 + b], cr[m][n], t);
                T[m][b] = t;
            }
        }
        // out[a][b] = sum_m av[m][a] * T[m][b]
        #pragma unroll
        for (int a = 0; a < 3; ++a) {
            #pragma unroll
            for (int b = 0; b < 5; ++b) {
                float acc = 0.0f;
                #pragma unroll
                for (int m = 0; m < 3; ++m)
                    acc = fmaf(av[m * 3 + a], T[m][b], acc);
                sO[tid * 15 + a * 5 + b] = acc;
            }
        }

        bar_lgkm();   // all sAB reads + sO writes complete; NO store drain

        // ---- flush sO -> global, nontemporal coalesced f32x4 ----
        float* obase = out + (size_t)tile * O_FL;
        #pragma unroll
        for (int jj = 0; jj < 4; ++jj) {
            int j = tid + jj * 320;
            if (j < 1200) {
                f32x4 v = *reinterpret_cast<const f32x4*>(&sO[4 * j]);
                __builtin_nontemporal_store(v, reinterpret_cast<f32x4*>(obase + 4 * j));
            }
        }

        // keep flush stores ordered before the g-dependent ds_writes so the
        // implicit wait is a counted vmcnt(4), not a store drain
        asm volatile("" ::: "memory");

        // ---- stage-write regs -> sAB (same buffer; reads all done) ----
        if (have_next) {
            *reinterpret_cast<f32x4*>(&sAB[tid * 4]) = g0;
            if (g1v)
                *reinterpret_cast<f32x4*>(&sAB[(tid + 320) * 4]) = g1;
        }

        bar_lgkm();
    }
}

extern "C" void kernel_launch(void* const* d_in, const int* in_sizes, int n_in,
                              void* d_out, int out_size, void* d_ws, size_t ws_size,
                              hipStream_t stream) {
    const float* A = (const float*)d_in[0];
    const float* B = (const float*)d_in[1];
    const float* C = (const float*)d_in[2];
    float* out = (float*)d_out;

    tb_kernel<<<GRID, 320, 0, stream>>>(A, B, C, out);
}